// Round 11
// baseline (34.127 us; speedup 1.0000x reference)
//
#include <hip/hip_runtime.h>

#define HOP   256
#define WINL  1024
#define PADL  384
#define NFR   4096
#define EXLEN (NFR * HOP)   // 1048576
#define OUTLEN EXLEN
#define TWOPI_OVER_WIN 0.006135923151542565f  // 2*pi/1024

#define SEGLEN 64     // own samples per segment
#define NSEG   16     // segments per frame
#define WARM   176    // warm-up; floor verified at 176/192/256
#define RND    16     // samples per round (live set ~118 VGPR incl. XN)
#define FRB    16     // frames per block
#define XSZ    5120   // xs floats: covers max idx 4879 (+prefetch overrun) in whole granules
// 15 rounds/thread = 5 iterations x 3 static phases (3-deep history rotation)

// One block = 16 frames x 16 segments (256 threads). x comes from an
// XOR-swizzled LDS image of the block's ex window; swizzle slot = i ^ ((i>>6)&31)
// spreads the stride-256 column reads across banks (<=2-way for full waves).
// KEY CHANGE vs round 10: next round's x is prefetched into XN[] BEFORE the
// FMA block, pinned by a compiler memory barrier so the ds_reads issue as one
// batch and their lgkmcnt wait lands AFTER ~950 cycles of FMA cover (the
// compiler was fusing load-with-use => 16 serialized ~200-cyc LDS round
// trips per round = the measured 80% stall).
__global__ __attribute__((amdgpu_waves_per_eu(1, 1))) __launch_bounds__(256)
void lpc_seg3(const float* __restrict__ ex,
              const float* __restrict__ lpc,
              float* __restrict__ y) {
    __shared__ float xs[XSZ];           // swizzled ex image
    __shared__ float lcoef[FRB * 27];   // padded coef rows
    const int tid = threadIdx.x;
    const int fg  = blockIdx.x;                    // 0..255
    const int bstart = fg * (FRB * HOP) - PADL;    // ex idx of xs[0]

    // ---- stage x: 20*256 consecutive floats, coalesced (guarded OOB -> 0) ----
#pragma unroll
    for (int q = 0; q < XSZ / 256; ++q) {
        const int i = q * 256 + tid;
        const int g = bstart + i;
        const float v = ((unsigned)g < (unsigned)EXLEN) ? ex[g] : 0.0f;
        xs[i ^ ((i >> 6) & 31)] = v;
    }
    // ---- stage coefs: 16 rows x 26, padded to 27 ----
    for (int i = tid; i < FRB * 26; i += 256)
        lcoef[(i / 26) * 27 + (i % 26)] = lpc[(size_t)fg * FRB * 26 + i];
    __syncthreads();

    const int seg = tid >> 4;        // 0..15
    const int fl  = tid & 15;        // 0..15
    const int f   = fg * FRB + fl;

    const float gain = lcoef[fl * 27];
    float a[26];
#pragma unroll
    for (int i = 1; i <= 25; ++i) a[i] = lcoef[fl * 27 + i];

    const int own = seg * SEGLEN;
    int tstart = own - WARM; if (tstart < 0) tstart = 0;   // multiple of 16

    float y0[RND], y1[RND], y2[RND];
#pragma unroll
    for (int i = 0; i < RND; ++i) { y0[i] = 0.0f; y1[i] = 0.0f; y2[i] = 0.0f; }

    int t0 = tstart;
    float* __restrict__ yrow = y + (size_t)f * WINL;

    // swizzled LDS read of 16 x-samples starting at frame-sample t (t mult of 16)
    auto XLOAD = [&](float (&X)[RND], int t) {
        const int baseF = fl * 256 + t;
        const int K = (baseF >> 6) & 31;
        const int K15 = K & 15;
        const int base2 = baseF ^ (K & 16);
#pragma unroll
        for (int i = 0; i < RND; ++i) X[i] = xs[base2 + (i ^ K15)];
    };

    float XC[RND], XN[RND];
    XLOAD(XC, t0);

    // y_t = gain*x_t - sum_{d=1..25} a_d y_{t-d}; taps d=2..25 in 3
    // independent chains, d=1 last (cross-sample critical path = 1 FMA).
    auto RD = [&](float (&W)[RND], float (&P1)[RND], float (&P2)[RND]) {
        XLOAD(XN, t0 + RND);               // prefetch next round's x (batch issue)
        asm volatile("" ::: "memory");     // pin: no sinking of the ds_reads
#pragma unroll
        for (int i = 0; i < RND; ++i) {
            float p0 = gain * XC[i], p1 = 0.0f, p2 = 0.0f;
#pragma unroll
            for (int d = 2; d <= 9; ++d) {       // j in [-9, 13]
                const int j = i - d;
                p0 = fmaf(-a[d], (j >= 0) ? W[j] : P1[RND + j], p0);
            }
#pragma unroll
            for (int d = 10; d <= 17; ++d) {     // j in [-17, 5]
                const int j = i - d;
                const float yv = (j >= 0) ? W[j] : ((j >= -RND) ? P1[RND + j] : P2[2 * RND + j]);
                p1 = fmaf(-a[d], yv, p1);
            }
#pragma unroll
            for (int d = 18; d <= 25; ++d) {     // j in [-25, -3]
                const int j = i - d;
                const float yv = (j >= -RND) ? P1[RND + j] : P2[2 * RND + j];
                p2 = fmaf(-a[d], yv, p2);
            }
            const float ym1 = (i >= 1) ? W[i - 1] : P1[RND - 1];
            W[i] = fmaf(-a[1], ym1, p0 + (p1 + p2));
        }
        if (t0 >= own && t0 < own + SEGLEN) {    // 4 owned rounds per thread
            float4* dst = reinterpret_cast<float4*>(yrow + t0);
#pragma unroll
            for (int q = 0; q < RND / 4; ++q)
                dst[q] = make_float4(W[4 * q], W[4 * q + 1], W[4 * q + 2], W[4 * q + 3]);
        }
#pragma unroll
        for (int i = 0; i < RND; ++i) XC[i] = XN[i];   // 16 v_mov; wait lands here,
        t0 += RND;                                     // after the FMA cover
    };

    for (int q = 0; q < 5; ++q) {   // 15 rounds, phase-static rotation
        RD(y0, y2, y1);
        RD(y1, y0, y2);
        RD(y2, y1, y0);
    }
}

// ---------------- gather: <=4 windowed contributions; analytic Hann + norm ----------------
__global__ __launch_bounds__(256) void ola_gather(const float* __restrict__ ws,
                                                  float* __restrict__ out) {
    int tid = blockIdx.x * 256 + threadIdx.x;
    int i4 = tid * 4;
    if (i4 >= OUTLEN) return;
    int p  = i4 + PADL;
    int fp = p >> 8;
    int r  = p & 255;       // 4-aligned; r..r+3 never crosses a 256 boundary
    float cth[4], sth[4];
#pragma unroll
    for (int e = 0; e < 4; ++e)
        __sincosf(TWOPI_OVER_WIN * (float)(r + e), &sth[e], &cth[e]);
    float num[4] = {0.f, 0.f, 0.f, 0.f};
    float den[4] = {0.f, 0.f, 0.f, 0.f};
#pragma unroll
    for (int j = 0; j < 4; ++j) {
        int f = fp - j;
        if (f >= 0 && f < NFR) {
            const float4 yv = *reinterpret_cast<const float4*>(
                ws + (size_t)f * WINL + (r + 256 * j));
            float yy[4] = {yv.x, yv.y, yv.z, yv.w};
#pragma unroll
            for (int e = 0; e < 4; ++e) {
                float w;
                if      (j == 0) w = 0.5f - 0.5f * cth[e];
                else if (j == 1) w = 0.5f + 0.5f * sth[e];
                else if (j == 2) w = 0.5f + 0.5f * cth[e];
                else             w = 0.5f - 0.5f * sth[e];
                num[e] = fmaf(yy[e], w, num[e]);
                den[e] += w;
            }
        }
    }
    float4 o;
    o.x = num[0] / den[0];
    o.y = num[1] / den[1];
    o.z = num[2] / den[2];
    o.w = num[3] / den[3];
    *reinterpret_cast<float4*>(out + i4) = o;
}

extern "C" void kernel_launch(void* const* d_in, const int* in_sizes, int n_in,
                              void* d_out, int out_size, void* d_ws, size_t ws_size,
                              hipStream_t stream) {
    const float* ex  = (const float*)d_in[0];
    const float* lpc = (const float*)d_in[1];
    float* out = (float*)d_out;
    float* yb  = (float*)d_ws;   // 16 MiB: y[f][t], fully overwritten each call
    lpc_seg3<<<NFR / FRB, 256, 0, stream>>>(ex, lpc, yb);
    ola_gather<<<(OUTLEN / 4) / 256, 256, 0, stream>>>(yb, out);
}